// Round 6
// baseline (339.565 us; speedup 1.0000x reference)
//
#include <hip/hip_runtime.h>
#include <hip/hip_cooperative_groups.h>
#include <math.h>

namespace cg = cooperative_groups;

#define SEQL 256

struct PC {
    const float* norm_b;
    const float* in_proj_w;
    const float* conv_w[3];
    const float* conv_b[3];
    const float* xproj_w[3];
    const float* dtproj_w[3];
    const float* dtproj_b[3];
    const float* A_log[3];
    const float* Dskip[3];
    const float* out_proj_w;
    const float* w1; const float* b1;
    const float* w2; const float* b2;
    const float* w3; const float* b3;
    float* h1;     // ws + 0   : 512 floats
    float* h2;     // ws + 512 : 256 floats
    float* row;    // ws + 768 : 100 floats
    float4* out4;
};

__device__ __forceinline__ float silu_f(float x)     { return x / (1.0f + expf(-x)); }
__device__ __forceinline__ float softplus_f(float x) { return x > 0.f ? x + log1pf(expf(-x)) : log1pf(expf(x)); }
__device__ __forceinline__ float elu_f(float x)      { return x > 0.f ? x : expm1f(x); }

// ---------------------------------------------------------------------------
// ONE cooperative dispatch, 512 blocks x 64 threads. R4's proven dataflow
// (each weight row read once grid-wide, coalesced, wave-per-row + shuffle
// reduce) with grid.sync() replacing kernel boundaries.
// ---------------------------------------------------------------------------
__global__ __launch_bounds__(64) void k_coop(PC p) {
    cg::grid_group grid = cg::this_grid();

    __shared__ float xs_c[3][4][2];   // [dir][class][d] post-conv silu'd x
    __shared__ float dl_c[3][4][2];   // [dir][class][d] delta
    __shared__ float hc[SEQL][49];    // q = (dir*2+d)*8 + k  (49-pad: conflict-free)
    __shared__ __align__(16) float yrow[SEQL];
    __shared__ __align__(16) float rowL[100];

    const int tid = threadIdx.x;
    const int bid = blockIdx.x;
    const float nb0 = p.norm_b[0];                  // LayerNorm over singleton axis == norm_b
    const float c0  = nb0 * p.in_proj_w[0];
    const float c1  = nb0 * p.in_proj_w[1];

    // ---- Phase A: 12 threads compute the 4 l-classes (l=0,1,2,>=3) ----
    if (tid < 12) {
        const int dir = tid >> 2, cls = tid & 3;
        const float* cw  = p.conv_w[dir];
        const float* cb  = p.conv_b[dir];
        const float* xp  = p.xproj_w[dir];
        const float* dtw = p.dtproj_w[dir];
        const float* dtb = p.dtproj_b[dir];
        float xsv[2];
        for (int d = 0; d < 2; ++d) {
            float s = 0.f;                           // same k-ascending order as reference
            for (int k = 3 - cls; k < 4; ++k) s += cw[d * 4 + k];
            xsv[d] = silu_f((d == 0 ? c0 : c1) * s + cb[d]);
            xs_c[dir][cls][d] = xsv[d];
        }
        const float xd0 = xp[0] * xsv[0] + xp[1] * xsv[1];   // DT_RANK = 1
        dl_c[dir][cls][0] = softplus_f(dtw[0] * xd0 + dtb[0]);
        dl_c[dir][cls][1] = softplus_f(dtw[1] * xd0 + dtb[1]);
    }
    __syncthreads();

    // ---- Phase B: 48 threads x 2 recurrences, register-constant for l>=3 ----
    if (tid < 48) {
        const int dir = tid / 16;
        const int r   = tid % 16;
        const int d   = r / 8;
        const int k   = r % 8;
        const int n0  = 2 * k, n1 = 2 * k + 1;
        const float* xp = p.xproj_w[dir];
        const float A0 = -expf(p.A_log[dir][d * 16 + n0]);
        const float A1 = -expf(p.A_log[dir][d * 16 + n1]);
        const float b00 = xp[(1 + n0) * 2],  b01 = xp[(1 + n0) * 2 + 1];
        const float b10 = xp[(1 + n1) * 2],  b11 = xp[(1 + n1) * 2 + 1];
        const float c00 = xp[(17 + n0) * 2], c01 = xp[(17 + n0) * 2 + 1];
        const float c10 = xp[(17 + n1) * 2], c11 = xp[(17 + n1) * 2 + 1];
        const int q = (dir * 2 + d) * 8 + k;

        float e0[4], f0[4], e1[4], f1[4], cp0[4], cp1[4];
        #pragma unroll
        for (int cls = 0; cls < 4; ++cls) {
            const float x0 = xs_c[dir][cls][0], x1 = xs_c[dir][cls][1];
            const float dlt = dl_c[dir][cls][d];
            const float u   = (d == 0) ? x0 : x1;
            const float du  = dlt * u;
            e0[cls] = expf(dlt * A0);  f0[cls] = du * (b00 * x0 + b01 * x1);
            e1[cls] = expf(dlt * A1);  f1[cls] = du * (b10 * x0 + b11 * x1);
            cp0[cls] = c00 * x0 + c01 * x1;
            cp1[cls] = c10 * x0 + c11 * x1;
        }
        float h0 = 0.f, h1v = 0.f;
        #pragma unroll
        for (int l = 0; l < 3; ++l) {               // classes 0..2, static indices
            h0  = e0[l] * h0  + f0[l];
            h1v = e1[l] * h1v + f1[l];
            hc[l][q] = h0 * cp0[l] + h1v * cp1[l];
        }
        const float E0 = e0[3], F0 = f0[3], E1 = e1[3], F1 = f1[3];
        const float P0 = cp0[3], P1 = cp1[3];
        for (int l = 3; l < SEQL; ++l) {            // two interleaved fma chains
            h0  = E0 * h0  + F0;
            h1v = E1 * h1v + F1;
            hc[l][q] = h0 * P0 + h1v * P1;
        }
    }
    __syncthreads();

    // ---- Phase C: reduce over n, Dskip/silu(z)/out_proj + l-permutations ----
    {
        const float opw0 = p.out_proj_w[0], opw1 = p.out_proj_w[1];
        const float sz0  = silu_f(nb0 * p.in_proj_w[2]);
        const float sz1  = silu_f(nb0 * p.in_proj_w[3]);
        for (int i = 0; i < 4; ++i) {
            const int t = i * 64 + tid;
            float acc = 0.f;
            for (int dir = 0; dir < 3; ++dir) {
                int lv;
                if      (dir == 0) lv = t;                          // forward
                else if (dir == 1) lv = SEQL - 1 - t;               // backward
                else               lv = ((t & 3) << 6) + (t >> 2);  // slice perm inverse
                const int cls = lv < 3 ? lv : 3;
                float s0 = 0.f, s1 = 0.f;
                for (int k = 0; k < 8; ++k) {
                    s0 += hc[lv][dir * 16 + k];
                    s1 += hc[lv][dir * 16 + 8 + k];
                }
                const float y0 = (s0 + xs_c[dir][cls][0] * p.Dskip[dir][0]) * sz0;
                const float y1 = (s1 + xs_c[dir][cls][1] * p.Dskip[dir][1]) * sz1;
                acc += opw0 * y0 + opw1 * y1;
            }
            yrow[t] = acc;
        }
    }
    __syncthreads();

    // ---- MLP1: block bid -> h1[bid] (w1 row read once grid-wide, coalesced) ----
    {
        const float4 w = reinterpret_cast<const float4*>(p.w1)[bid * 64 + tid];
        const float4 y = reinterpret_cast<const float4*>(yrow)[tid];
        float s = w.x * y.x + w.y * y.y + w.z * y.z + w.w * y.w;
        for (int m = 1; m < 64; m <<= 1) s += __shfl_xor(s, m);
        if (tid == 0) p.h1[bid] = elu_f(s + p.b1[bid]);
    }
    grid.sync();

    // ---- MLP2: blocks 0..255 -> h2[bid] ----
    if (bid < 256) {
        const float4* wr = reinterpret_cast<const float4*>(p.w2 + bid * 512);
        const float4* hv = reinterpret_cast<const float4*>(p.h1);
        const float4 a = wr[tid],      x = hv[tid];
        const float4 b = wr[tid + 64], y = hv[tid + 64];
        float s = a.x * x.x + a.y * x.y + a.z * x.z + a.w * x.w
                + b.x * y.x + b.y * y.y + b.z * y.z + b.w * y.w;
        for (int m = 1; m < 64; m <<= 1) s += __shfl_xor(s, m);
        if (tid == 0) p.h2[bid] = elu_f(s + p.b2[bid]);
    }
    grid.sync();

    // ---- MLP3: blocks 0..99 -> row[bid] ----
    if (bid < 100) {
        const float4 w = reinterpret_cast<const float4*>(p.w3 + bid * 256)[tid];
        const float4 h = reinterpret_cast<const float4*>(p.h2)[tid];
        float s = w.x * h.x + w.y * h.y + w.z * h.z + w.w * h.w;
        for (int m = 1; m < 64; m <<= 1) s += __shfl_xor(s, m);
        if (tid == 0) p.row[bid] = s + p.b3[bid];
    }
    grid.sync();

    // ---- Broadcast: block writes its 400-float4 slice of 8192x100 output ----
    {
        if (tid < 25) reinterpret_cast<float4*>(rowL)[tid] =
                          reinterpret_cast<const float4*>(p.row)[tid];
        __syncthreads();
        const float4* rowL4 = reinterpret_cast<const float4*>(rowL);
        const int base = bid * 400;
        #pragma unroll
        for (int i = 0; i < 7; ++i) {
            const int k = i * 64 + tid;
            if (k < 400) {
                const int idx = base + k;
                p.out4[idx] = rowL4[idx % 25];
            }
        }
    }
}

extern "C" void kernel_launch(void* const* d_in, const int* in_sizes, int n_in,
                              void* d_out, int out_size, void* d_ws, size_t ws_size,
                              hipStream_t stream) {
    const float* const* in = (const float* const*)d_in;
    PC p;
    p.norm_b    = in[2];
    p.in_proj_w = in[3];
    for (int dir = 0; dir < 3; ++dir) {
        const int base = 4 + dir * 7;
        p.conv_w[dir]   = in[base + 0];
        p.conv_b[dir]   = in[base + 1];
        p.xproj_w[dir]  = in[base + 2];
        p.dtproj_w[dir] = in[base + 3];
        p.dtproj_b[dir] = in[base + 4];
        p.A_log[dir]    = in[base + 5];
        p.Dskip[dir]    = in[base + 6];
    }
    p.out_proj_w = in[25];
    p.w1 = in[26]; p.b1 = in[27];
    p.w2 = in[28]; p.b2 = in[29];
    p.w3 = in[30]; p.b3 = in[31];

    float* ws = (float*)d_ws;
    p.h1  = ws;            // 512 floats
    p.h2  = ws + 512;      // 256 floats
    p.row = ws + 768;      // 100 floats
    p.out4 = (float4*)d_out;

    void* args[] = { &p };
    hipLaunchCooperativeKernel((void*)k_coop, dim3(512), dim3(64), args, 0, stream);
}

// Round 8
// 186.547 us; speedup vs baseline: 1.8203x; 1.8203x over previous
//
#include <hip/hip_runtime.h>
#include <math.h>

#define SEQL 256

struct PK {
    const float* norm_b;
    const float* in_proj_w;
    const float* conv_w[3];
    const float* conv_b[3];
    const float* xproj_w[3];
    const float* dtproj_w[3];
    const float* dtproj_b[3];
    const float* A_log[3];
    const float* Dskip[3];
    const float* out_proj_w;
    const float* w1; const float* b1;
    float* h1;                      // ws + 0 : 512 floats
};

__device__ __forceinline__ float silu_f(float x)     { return x / (1.0f + expf(-x)); }
__device__ __forceinline__ float softplus_f(float x) { return x > 0.f ? x + log1pf(expf(-x)) : log1pf(expf(x)); }
__device__ __forceinline__ float elu_f(float x)      { return x > 0.f ? x : expm1f(x); }

// ---------------------------------------------------------------------------
// K1 (verbatim R4, proven at 149 us / absmax 0.0): block j of 512 redundantly
// runs the batch-constant mamba pipeline (register-constant fma chains), then
// computes h1[j] = elu(w1[j,:] . yrow + b1[j]) with one coalesced row read.
// ---------------------------------------------------------------------------
__global__ __launch_bounds__(64) void k_scan_mlp1(PK p) {
    __shared__ float xs_c[3][4][2];   // [dir][class][d] post-conv silu'd x
    __shared__ float dl_c[3][4][2];   // [dir][class][d] delta
    __shared__ float hc[SEQL][49];    // q = (dir*2+d)*8 + k  (49-pad: conflict-free)
    __shared__ __align__(16) float yrow[SEQL];

    const int tid = threadIdx.x;
    const float nb0 = p.norm_b[0];                  // LayerNorm over singleton axis == norm_b
    const float c0  = nb0 * p.in_proj_w[0];
    const float c1  = nb0 * p.in_proj_w[1];

    // ---- Phase A: 12 threads compute the 4 l-classes (l=0,1,2,>=3) ----
    if (tid < 12) {
        const int dir = tid >> 2, cls = tid & 3;
        const float* cw  = p.conv_w[dir];
        const float* cb  = p.conv_b[dir];
        const float* xp  = p.xproj_w[dir];
        const float* dtw = p.dtproj_w[dir];
        const float* dtb = p.dtproj_b[dir];
        float xsv[2];
        for (int d = 0; d < 2; ++d) {
            float s = 0.f;                           // same k-ascending order as reference
            for (int k = 3 - cls; k < 4; ++k) s += cw[d * 4 + k];
            xsv[d] = silu_f((d == 0 ? c0 : c1) * s + cb[d]);
            xs_c[dir][cls][d] = xsv[d];
        }
        const float xd0 = xp[0] * xsv[0] + xp[1] * xsv[1];   // DT_RANK = 1
        dl_c[dir][cls][0] = softplus_f(dtw[0] * xd0 + dtb[0]);
        dl_c[dir][cls][1] = softplus_f(dtw[1] * xd0 + dtb[1]);
    }
    __syncthreads();

    // ---- Phase B: 48 threads x 2 recurrences, register-constant for l>=3 ----
    if (tid < 48) {
        const int dir = tid / 16;
        const int r   = tid % 16;
        const int d   = r / 8;
        const int k   = r % 8;
        const int n0  = 2 * k, n1 = 2 * k + 1;
        const float* xp = p.xproj_w[dir];
        const float A0 = -expf(p.A_log[dir][d * 16 + n0]);
        const float A1 = -expf(p.A_log[dir][d * 16 + n1]);
        const float b00 = xp[(1 + n0) * 2],  b01 = xp[(1 + n0) * 2 + 1];
        const float b10 = xp[(1 + n1) * 2],  b11 = xp[(1 + n1) * 2 + 1];
        const float c00 = xp[(17 + n0) * 2], c01 = xp[(17 + n0) * 2 + 1];
        const float c10 = xp[(17 + n1) * 2], c11 = xp[(17 + n1) * 2 + 1];
        const int q = (dir * 2 + d) * 8 + k;

        float e0[4], f0[4], e1[4], f1[4], cp0[4], cp1[4];
        #pragma unroll
        for (int cls = 0; cls < 4; ++cls) {
            const float x0 = xs_c[dir][cls][0], x1 = xs_c[dir][cls][1];
            const float dlt = dl_c[dir][cls][d];
            const float u   = (d == 0) ? x0 : x1;
            const float du  = dlt * u;
            e0[cls] = expf(dlt * A0);  f0[cls] = du * (b00 * x0 + b01 * x1);
            e1[cls] = expf(dlt * A1);  f1[cls] = du * (b10 * x0 + b11 * x1);
            cp0[cls] = c00 * x0 + c01 * x1;
            cp1[cls] = c10 * x0 + c11 * x1;
        }
        float h0 = 0.f, h1v = 0.f;
        #pragma unroll
        for (int l = 0; l < 3; ++l) {               // classes 0..2, static indices
            h0  = e0[l] * h0  + f0[l];
            h1v = e1[l] * h1v + f1[l];
            hc[l][q] = h0 * cp0[l] + h1v * cp1[l];
        }
        const float E0 = e0[3], F0 = f0[3], E1 = e1[3], F1 = f1[3];
        const float P0 = cp0[3], P1 = cp1[3];
        for (int l = 3; l < SEQL; ++l) {            // two interleaved fma chains
            h0  = E0 * h0  + F0;
            h1v = E1 * h1v + F1;
            hc[l][q] = h0 * P0 + h1v * P1;
        }
    }
    __syncthreads();

    // ---- Phase C: reduce over n, Dskip/silu(z)/out_proj + l-permutations ----
    {
        const float opw0 = p.out_proj_w[0], opw1 = p.out_proj_w[1];
        const float sz0  = silu_f(nb0 * p.in_proj_w[2]);
        const float sz1  = silu_f(nb0 * p.in_proj_w[3]);
        for (int i = 0; i < 4; ++i) {
            const int t = i * 64 + tid;
            float acc = 0.f;
            for (int dir = 0; dir < 3; ++dir) {
                int lv;
                if      (dir == 0) lv = t;                          // forward
                else if (dir == 1) lv = SEQL - 1 - t;               // backward
                else               lv = ((t & 3) << 6) + (t >> 2);  // slice perm inverse
                const int cls = lv < 3 ? lv : 3;
                float s0 = 0.f, s1 = 0.f;
                for (int k = 0; k < 8; ++k) {
                    s0 += hc[lv][dir * 16 + k];
                    s1 += hc[lv][dir * 16 + 8 + k];
                }
                const float y0 = (s0 + xs_c[dir][cls][0] * p.Dskip[dir][0]) * sz0;
                const float y1 = (s1 + xs_c[dir][cls][1] * p.Dskip[dir][1]) * sz1;
                acc += opw0 * y0 + opw1 * y1;
            }
            yrow[t] = acc;
        }
    }
    __syncthreads();

    // ---- MLP1 row j: 64 lanes x 1 float4, butterfly reduce ----
    {
        const int j = blockIdx.x;
        const float4 w = reinterpret_cast<const float4*>(p.w1)[j * 64 + tid];
        const float4 y = reinterpret_cast<const float4*>(yrow)[tid];
        float s = w.x * y.x + w.y * y.y + w.z * y.z + w.w * y.w;
        for (int m = 1; m < 64; m <<= 1) s += __shfl_xor(s, m);
        if (tid == 0) p.h1[j] = elu_f(s + p.b1[j]);
    }
}

// ---------------------------------------------------------------------------
// K2: 64 blocks x 256 threads, NO inter-block sync. Each block redundantly
// computes all of h2 (wave-per-row over LDS-resident h1; w2 = 512 KB is
// L2-resident per XCD so redundancy is cheap), then row[100], then writes its
// 3200-float4 slice of the 8192x100 broadcast output.
// ---------------------------------------------------------------------------
__global__ __launch_bounds__(256) void k_tail(const float* __restrict__ w2, const float* __restrict__ b2,
                                              const float* __restrict__ w3, const float* __restrict__ b3,
                                              const float* __restrict__ h1, float4* __restrict__ out4) {
    __shared__ __align__(16) float h1L[512];
    __shared__ __align__(16) float h2L[256];
    __shared__ __align__(16) float rowL[100];
    const int t = threadIdx.x;
    const int wave = t >> 6, lane = t & 63;

    if (t < 128) reinterpret_cast<float4*>(h1L)[t] = reinterpret_cast<const float4*>(h1)[t];
    __syncthreads();

    // ---- MLP2: 64 iterations/wave, j = jj*4 + wave (adjacent rows across waves) ----
    {
        const float4* hv = reinterpret_cast<const float4*>(h1L);
        const float4 x = hv[lane], y = hv[lane + 64];
        for (int jj = 0; jj < 64; ++jj) {
            const int j = jj * 4 + wave;
            const float4* wr = reinterpret_cast<const float4*>(w2 + j * 512);
            const float4 a = wr[lane], b = wr[lane + 64];
            float s = a.x * x.x + a.y * x.y + a.z * x.z + a.w * x.w
                    + b.x * y.x + b.y * y.y + b.z * y.z + b.w * y.w;
            for (int m = 1; m < 64; m <<= 1) s += __shfl_xor(s, m);
            if (lane == 0) h2L[j] = elu_f(s + b2[j]);
        }
    }
    __syncthreads();

    // ---- MLP3: wave-per-row, 25 iterations ----
    {
        const float4* hv = reinterpret_cast<const float4*>(h2L);
        const float4 h = hv[lane];
        for (int jj = 0; jj < 25; ++jj) {
            const int j = wave * 25 + jj;
            const float4 w = reinterpret_cast<const float4*>(w3)[j * 64 + lane];
            float s = w.x * h.x + w.y * h.y + w.z * h.z + w.w * h.w;
            for (int m = 1; m < 64; m <<= 1) s += __shfl_xor(s, m);
            if (lane == 0) rowL[j] = s + b3[j];
        }
    }
    __syncthreads();

    // ---- Broadcast: this block's 3200-float4 slice (3200 % 25 == 0) ----
    {
        const float4* rowL4 = reinterpret_cast<const float4*>(rowL);
        const int base = blockIdx.x * 3200;
        #pragma unroll
        for (int i = 0; i < 13; ++i) {
            const int k = i * 256 + t;
            if (k < 3200) out4[base + k] = rowL4[k % 25];
        }
    }
}

extern "C" void kernel_launch(void* const* d_in, const int* in_sizes, int n_in,
                              void* d_out, int out_size, void* d_ws, size_t ws_size,
                              hipStream_t stream) {
    const float* const* in = (const float* const*)d_in;
    PK p;
    p.norm_b    = in[2];
    p.in_proj_w = in[3];
    for (int dir = 0; dir < 3; ++dir) {
        const int base = 4 + dir * 7;
        p.conv_w[dir]   = in[base + 0];
        p.conv_b[dir]   = in[base + 1];
        p.xproj_w[dir]  = in[base + 2];
        p.dtproj_w[dir] = in[base + 3];
        p.dtproj_b[dir] = in[base + 4];
        p.A_log[dir]    = in[base + 5];
        p.Dskip[dir]    = in[base + 6];
    }
    p.out_proj_w = in[25];
    p.w1 = in[26]; p.b1 = in[27];
    const float* w2 = in[28]; const float* b2 = in[29];
    const float* w3 = in[30]; const float* b3 = in[31];

    float* ws = (float*)d_ws;
    p.h1 = ws;                                     // 512 floats

    k_scan_mlp1<<<512, 64, 0, stream>>>(p);
    k_tail<<<64, 256, 0, stream>>>(w2, b2, w3, b3, p.h1, (float4*)d_out);
}

// Round 9
// 148.067 us; speedup vs baseline: 2.2933x; 1.2599x over previous
//
#include <hip/hip_runtime.h>
#include <math.h>

#define SEQL 256

struct PK {
    const float* norm_b;
    const float* in_proj_w;
    const float* conv_w[3];
    const float* conv_b[3];
    const float* xproj_w[3];
    const float* dtproj_w[3];
    const float* dtproj_b[3];
    const float* A_log[3];
    const float* Dskip[3];
    const float* out_proj_w;
    const float* w1; const float* b1;
    float* h1;                      // ws + 0 : 512 floats
};

__device__ __forceinline__ float silu_f(float x)     { return x / (1.0f + expf(-x)); }
__device__ __forceinline__ float softplus_f(float x) { return x > 0.f ? x + log1pf(expf(-x)) : log1pf(expf(x)); }
__device__ __forceinline__ float elu_f(float x)      { return x > 0.f ? x : expm1f(x); }

// ---------------------------------------------------------------------------
// K1: block j (512 blocks x 64 threads) redundantly runs the batch-constant
// mamba pipeline (cheap: conv input is constant => only 4 distinct activation
// classes; for l>=3 the recurrence uses pure register constants), then
// computes h1[j] = elu(w1[j,:] . yrow + b1[j]).
// ---------------------------------------------------------------------------
__global__ __launch_bounds__(64) void k_scan_mlp1(PK p) {
    __shared__ float xs_c[3][4][2];   // [dir][class][d] post-conv silu'd x
    __shared__ float dl_c[3][4][2];   // [dir][class][d] delta
    __shared__ float hc[SEQL][49];    // q = (dir*2+d)*8 + k  (49-pad: conflict-free)
    __shared__ __align__(16) float yrow[SEQL];

    const int tid = threadIdx.x;
    const float nb0 = p.norm_b[0];                  // LayerNorm over singleton axis == norm_b
    const float c0  = nb0 * p.in_proj_w[0];
    const float c1  = nb0 * p.in_proj_w[1];

    // ---- Phase A: 12 threads compute the 4 l-classes (l=0,1,2,>=3) ----
    if (tid < 12) {
        const int dir = tid >> 2, cls = tid & 3;
        const float* cw  = p.conv_w[dir];
        const float* cb  = p.conv_b[dir];
        const float* xp  = p.xproj_w[dir];
        const float* dtw = p.dtproj_w[dir];
        const float* dtb = p.dtproj_b[dir];
        float xsv[2];
        for (int d = 0; d < 2; ++d) {
            float s = 0.f;                           // same k-ascending order as reference
            for (int k = 3 - cls; k < 4; ++k) s += cw[d * 4 + k];
            xsv[d] = silu_f((d == 0 ? c0 : c1) * s + cb[d]);
            xs_c[dir][cls][d] = xsv[d];
        }
        const float xd0 = xp[0] * xsv[0] + xp[1] * xsv[1];   // DT_RANK = 1
        dl_c[dir][cls][0] = softplus_f(dtw[0] * xd0 + dtb[0]);
        dl_c[dir][cls][1] = softplus_f(dtw[1] * xd0 + dtb[1]);
    }
    __syncthreads();

    // ---- Phase B: 48 threads x 2 recurrences, register-constant for l>=3 ----
    if (tid < 48) {
        const int dir = tid / 16;
        const int r   = tid % 16;
        const int d   = r / 8;
        const int k   = r % 8;
        const int n0  = 2 * k, n1 = 2 * k + 1;
        const float* xp = p.xproj_w[dir];
        const float A0 = -expf(p.A_log[dir][d * 16 + n0]);
        const float A1 = -expf(p.A_log[dir][d * 16 + n1]);
        const float b00 = xp[(1 + n0) * 2],  b01 = xp[(1 + n0) * 2 + 1];
        const float b10 = xp[(1 + n1) * 2],  b11 = xp[(1 + n1) * 2 + 1];
        const float c00 = xp[(17 + n0) * 2], c01 = xp[(17 + n0) * 2 + 1];
        const float c10 = xp[(17 + n1) * 2], c11 = xp[(17 + n1) * 2 + 1];
        const int q = (dir * 2 + d) * 8 + k;

        float e0[4], f0[4], e1[4], f1[4], cp0[4], cp1[4];
        #pragma unroll
        for (int cls = 0; cls < 4; ++cls) {
            const float x0 = xs_c[dir][cls][0], x1 = xs_c[dir][cls][1];
            const float dlt = dl_c[dir][cls][d];
            const float u   = (d == 0) ? x0 : x1;
            const float du  = dlt * u;
            e0[cls] = expf(dlt * A0);  f0[cls] = du * (b00 * x0 + b01 * x1);
            e1[cls] = expf(dlt * A1);  f1[cls] = du * (b10 * x0 + b11 * x1);
            cp0[cls] = c00 * x0 + c01 * x1;
            cp1[cls] = c10 * x0 + c11 * x1;
        }
        float h0 = 0.f, h1v = 0.f;
        #pragma unroll
        for (int l = 0; l < 3; ++l) {               // classes 0..2, static indices
            h0  = e0[l] * h0  + f0[l];
            h1v = e1[l] * h1v + f1[l];
            hc[l][q] = h0 * cp0[l] + h1v * cp1[l];
        }
        const float E0 = e0[3], F0 = f0[3], E1 = e1[3], F1 = f1[3];
        const float P0 = cp0[3], P1 = cp1[3];
        for (int l = 3; l < SEQL; ++l) {            // two interleaved fma chains
            h0  = E0 * h0  + F0;
            h1v = E1 * h1v + F1;
            hc[l][q] = h0 * P0 + h1v * P1;
        }
    }
    __syncthreads();

    // ---- Phase C: reduce over n, Dskip/silu(z)/out_proj + l-permutations ----
    {
        const float opw0 = p.out_proj_w[0], opw1 = p.out_proj_w[1];
        const float sz0  = silu_f(nb0 * p.in_proj_w[2]);
        const float sz1  = silu_f(nb0 * p.in_proj_w[3]);
        for (int i = 0; i < 4; ++i) {
            const int t = i * 64 + tid;
            float acc = 0.f;
            for (int dir = 0; dir < 3; ++dir) {
                int lv;
                if      (dir == 0) lv = t;                          // forward
                else if (dir == 1) lv = SEQL - 1 - t;               // backward
                else               lv = ((t & 3) << 6) + (t >> 2);  // slice perm inverse
                const int cls = lv < 3 ? lv : 3;
                float s0 = 0.f, s1 = 0.f;
                for (int k = 0; k < 8; ++k) {
                    s0 += hc[lv][dir * 16 + k];
                    s1 += hc[lv][dir * 16 + 8 + k];
                }
                const float y0 = (s0 + xs_c[dir][cls][0] * p.Dskip[dir][0]) * sz0;
                const float y1 = (s1 + xs_c[dir][cls][1] * p.Dskip[dir][1]) * sz1;
                acc += opw0 * y0 + opw1 * y1;
            }
            yrow[t] = acc;
        }
    }
    __syncthreads();

    // ---- MLP1 row j: 64 lanes x 1 float4, butterfly reduce ----
    {
        const int j = blockIdx.x;
        const float4 w = reinterpret_cast<const float4*>(p.w1)[j * 64 + tid];
        const float4 y = reinterpret_cast<const float4*>(yrow)[tid];
        float s = w.x * y.x + w.y * y.y + w.z * y.z + w.w * y.w;
        for (int m = 1; m < 64; m <<= 1) s += __shfl_xor(s, m);
        if (tid == 0) p.h1[j] = elu_f(s + p.b1[j]);
    }
}

// ---------------------------------------------------------------------------
// K2: h2[j] = elu(w2[j,:] . h1 + b2[j]); 256 blocks x 64 lanes, 8 elems/lane.
// ---------------------------------------------------------------------------
__global__ __launch_bounds__(64) void k_mlp2(const float* __restrict__ w2, const float* __restrict__ b2,
                                             const float* __restrict__ h1, float* __restrict__ h2) {
    const int j = blockIdx.x, t = threadIdx.x;
    const float4* wr = reinterpret_cast<const float4*>(w2 + j * 512);
    const float4* hv = reinterpret_cast<const float4*>(h1);
    const float4 a = wr[t],      x = hv[t];
    const float4 b = wr[t + 64], y = hv[t + 64];
    float s = a.x * x.x + a.y * x.y + a.z * x.z + a.w * x.w
            + b.x * y.x + b.y * y.y + b.z * y.z + b.w * y.w;
    for (int m = 1; m < 64; m <<= 1) s += __shfl_xor(s, m);
    if (t == 0) h2[j] = elu_f(s + b2[j]);
}

// ---------------------------------------------------------------------------
// K3: each of 200 blocks redundantly computes row[100] = w3 . h2 + b3
// (w3 = 100 KB, L2-broadcast), then writes its 1024-float4 output slice.
// ---------------------------------------------------------------------------
__global__ __launch_bounds__(256) void k_mlp3_bcast(const float* __restrict__ w3, const float* __restrict__ b3,
                                                    const float* __restrict__ h2, float4* __restrict__ out4) {
    __shared__ __align__(16) float h2L[256];
    __shared__ __align__(16) float rowL[100];
    const int t = threadIdx.x;
    if (t < 64) reinterpret_cast<float4*>(h2L)[t] = reinterpret_cast<const float4*>(h2)[t];
    __syncthreads();
    const int wave = t >> 6, lane = t & 63;
    for (int jj = 0; jj < 25; ++jj) {
        const int j = wave * 25 + jj;
        const float4 w = reinterpret_cast<const float4*>(w3)[j * 64 + lane];
        const float4 h = reinterpret_cast<const float4*>(h2L)[lane];
        float s = w.x * h.x + w.y * h.y + w.z * h.z + w.w * h.w;
        for (int m = 1; m < 64; m <<= 1) s += __shfl_xor(s, m);
        if (lane == 0) rowL[j] = s + b3[j];
    }
    __syncthreads();
    const float4* rowL4 = reinterpret_cast<const float4*>(rowL);
    const int base = blockIdx.x * 1024;
    #pragma unroll
    for (int i = 0; i < 4; ++i) {
        const int idx = base + i * 256 + t;
        out4[idx] = rowL4[idx % 25];
    }
}

extern "C" void kernel_launch(void* const* d_in, const int* in_sizes, int n_in,
                              void* d_out, int out_size, void* d_ws, size_t ws_size,
                              hipStream_t stream) {
    const float* const* in = (const float* const*)d_in;
    PK p;
    p.norm_b    = in[2];
    p.in_proj_w = in[3];
    for (int dir = 0; dir < 3; ++dir) {
        const int base = 4 + dir * 7;
        p.conv_w[dir]   = in[base + 0];
        p.conv_b[dir]   = in[base + 1];
        p.xproj_w[dir]  = in[base + 2];
        p.dtproj_w[dir] = in[base + 3];
        p.dtproj_b[dir] = in[base + 4];
        p.A_log[dir]    = in[base + 5];
        p.Dskip[dir]    = in[base + 6];
    }
    p.out_proj_w = in[25];
    p.w1 = in[26]; p.b1 = in[27];
    const float* w2 = in[28]; const float* b2 = in[29];
    const float* w3 = in[30]; const float* b3 = in[31];

    float* ws = (float*)d_ws;
    float* h1 = ws;              // 512 floats
    float* h2 = ws + 512;        // 256 floats
    p.h1 = h1;

    k_scan_mlp1<<<512, 64, 0, stream>>>(p);
    k_mlp2     <<<256, 64, 0, stream>>>(w2, b2, h1, h2);
    k_mlp3_bcast<<<200, 256, 0, stream>>>(w3, b3, h2, (float4*)d_out);
}